// Round 4
// baseline (248.945 us; speedup 1.0000x reference)
//
#include <hip/hip_runtime.h>
#include <cstdint>
#include <cstddef>

#define D 256
#define E 256
#define T 128
#define QIN 640   // D + E + T
#define P 8
#define R 16      // batch rows per block (kernel 1)
#define KP 648    // qa row stride in ushort
#define DP 260    // qpre row stride in floats

typedef __attribute__((ext_vector_type(8))) short bf16x8;
typedef __attribute__((ext_vector_type(4))) float f32x4;

__device__ __forceinline__ ushort f2bf(float f) {   // RNE fp32->bf16
  uint32_t u = __float_as_uint(f);
  u += 0x7fffu + ((u >> 16) & 1u);
  return (ushort)(u >> 16);
}
__device__ __forceinline__ float bf2f(ushort h) {
  return __uint_as_float(((uint32_t)h) << 16);
}

__device__ __forceinline__ float wsum(float v) {
#pragma unroll
  for (int o = 32; o > 0; o >>= 1) v += __shfl_xor(v, o, 64);
  return v;
}

__device__ __forceinline__ void wsum2(float& a, float& b) {
#pragma unroll
  for (int o = 32; o > 0; o >>= 1) {
    a += __shfl_xor(a, o, 64);
    b += __shfl_xor(b, o, 64);
  }
}

__device__ __forceinline__ float clampf(float x, float lo, float hi) {
  return fminf(fmaxf(x, lo), hi);
}

// W2[((k>>3)*D + n)*8 + (k&7)] = bf16(Wq[n][k])
__global__ void prep_w2_kernel(const float* __restrict__ Wq, ushort* __restrict__ W2) {
  const int idx = blockIdx.x * 256 + threadIdx.x;
  const int n = idx / QIN;
  const int k = idx - n * QIN;
  W2[((((k >> 3) * D + n) << 3)) + (k & 7)] = f2bf(Wq[idx]);
}

// ---------------- kernel 1: query proj + LN + tanh + normalize -> qn (bf16) ----------------
__global__ __launch_bounds__(256, 4) void qn_kernel(
    const float* __restrict__ raw, const float* __restrict__ edge,
    const float* __restrict__ tim, const ushort* __restrict__ W2,
    const float* __restrict__ bq, const float* __restrict__ lnw,
    const float* __restrict__ lnb, ushort* __restrict__ qn) {
  __shared__ ushort qa[R][KP];    // 20.25 KB
  __shared__ float qpre[R][DP];   // 16.25 KB

  const int tid = threadIdx.x;
  const int r0 = blockIdx.x * R;

  // stage q_in rows -> bf16 LDS (coalesced float4 reads)
#pragma unroll
  for (int it = 0; it < (R * QIN / 4) / 256; ++it) {
    const int flat = it * 256 + tid;
    const int r = flat / (QIN / 4);
    const int p4 = (flat - r * (QIN / 4)) * 4;
    const size_t g = (size_t)(r0 + r);
    float4 v;
    if (p4 < D)          v = *(const float4*)(raw + g * D + p4);
    else if (p4 < D + E) v = *(const float4*)(edge + g * E + (p4 - D));
    else                 v = *(const float4*)(tim + g * T + (p4 - D - E));
    ushort4 h;
    h.x = f2bf(v.x); h.y = f2bf(v.y); h.z = f2bf(v.z); h.w = f2bf(v.w);
    *(ushort4*)&qa[r][p4] = h;
  }
  __syncthreads();

  const int w = tid >> 6;
  const int lane = tid & 63;
  const int lr = lane & 15;
  const int lh = lane >> 4;

  // GEMM: 4 waves x 4 col-tiles of 16, K=640 in steps of 32
  {
    f32x4 acc[4];
#pragma unroll
    for (int c = 0; c < 4; ++c) acc[c] = (f32x4){0.f, 0.f, 0.f, 0.f};

    for (int kb = 0; kb < QIN; kb += 32) {
      const bf16x8 af = *(const bf16x8*)&qa[lr][kb + lh * 8];
#pragma unroll
      for (int c = 0; c < 4; ++c) {
        const int n = w * 64 + c * 16 + lr;
        const bf16x8 bfv = *(const bf16x8*)&W2[(((kb >> 3) + lh) * D + n) << 3];
        acc[c] = __builtin_amdgcn_mfma_f32_16x16x32_bf16(af, bfv, acc[c], 0, 0, 0);
      }
    }
    // C/D layout: col = lane&15, row = (lane>>4)*4 + reg
#pragma unroll
    for (int c = 0; c < 4; ++c) {
      const int n = w * 64 + c * 16 + lr;
      const float bqv = bq[n];
#pragma unroll
      for (int i = 0; i < 4; ++i) qpre[lh * 4 + i][n] = acc[c][i] + bqv;
    }
  }
  __syncthreads();

  // epilogue: LN + tanh + normalize, write bf16 qn
  const float4 lnw4 = *(const float4*)(lnw + 4 * lane);
  const float4 lnb4 = *(const float4*)(lnb + 4 * lane);
  const float lw[4] = {lnw4.x, lnw4.y, lnw4.z, lnw4.w};
  const float lb[4] = {lnb4.x, lnb4.y, lnb4.z, lnb4.w};

  for (int r = w; r < R; r += 4) {
    const size_t g = (size_t)(r0 + r);
    const float4 x4 = *(const float4*)&qpre[r][4 * lane];
    float x[4] = {x4.x, x4.y, x4.z, x4.w};
    const float mu = wsum(x[0] + x[1] + x[2] + x[3]) * (1.0f / 256.0f);
    float dx[4];
    float v = 0.f;
#pragma unroll
    for (int i = 0; i < 4; ++i) { dx[i] = x[i] - mu; v += dx[i] * dx[i]; }
    const float rstd = 1.0f / sqrtf(wsum(v) * (1.0f / 256.0f) + 1e-6f);
    float q[4];
    float qs = 0.f;
#pragma unroll
    for (int i = 0; i < 4; ++i) {
      q[i] = tanhf(dx[i] * rstd * lw[i] + lb[i]);
      qs += q[i] * q[i];
    }
    const float qinv = 1.0f / fmaxf(sqrtf(wsum(qs)), 1e-6f);
    ushort4 h;
    h.x = f2bf(q[0] * qinv); h.y = f2bf(q[1] * qinv);
    h.z = f2bf(q[2] * qinv); h.w = f2bf(q[3] * qinv);
    *(ushort4*)(qn + g * D + 4 * lane) = h;
  }
}

// ---------------- kernel 2: pure streaming (no LDS, no barriers) ----------------
__global__ __launch_bounds__(256, 5) void stream_kernel(
    const float* __restrict__ raw, const float* __restrict__ tim,
    const float* __restrict__ proto, const ushort* __restrict__ qn,
    const float* __restrict__ Wg, const float* __restrict__ bg,
    const float* __restrict__ temp, const float* __restrict__ lnw,
    const float* __restrict__ lnb, float* __restrict__ out) {
  const int tid = threadIdx.x;
  const int w = tid >> 6;
  const int lane = tid & 63;
  const size_t g = (size_t)blockIdx.x * 4 + w;   // one wave per row

  // issue ALL global loads up front
  const float* pb = proto + (g * P) * D + 4 * lane;
  float4 pv[P];
#pragma unroll
  for (int p = 0; p < P; ++p) pv[p] = *(const float4*)(pb + (size_t)p * D);
  const ushort4 qh = *(const ushort4*)(qn + g * D + 4 * lane);
  const float4 raw4 = *(const float4*)(raw + g * D + 4 * lane);
  const float2 t2 = *(const float2*)(tim + g * T + 2 * lane);

  const float4 lnw4 = *(const float4*)(lnw + 4 * lane);
  const float4 lnb4 = *(const float4*)(lnb + 4 * lane);
  const float4 wga = *(const float4*)(Wg + 4 * lane);
  const float4 wgb = *(const float4*)(Wg + D + 4 * lane);
  const float2 wgt = *(const float2*)(Wg + 2 * D + 2 * lane);
  const float bgv = bg[0];
  const float invt = 1.0f / (clampf(temp[0], 0.5f, 5.0f) + 0.01f);

  const float q[4] = {bf2f(qh.x), bf2f(qh.y), bf2f(qh.z), bf2f(qh.w)};

  // cosine sim (qn already unit-norm)
  float sim[P];
#pragma unroll
  for (int p = 0; p < P; ++p) {
    const float4 p4 = pv[p];
    float dt = q[0] * p4.x + q[1] * p4.y + q[2] * p4.z + q[3] * p4.w;
    float pn = p4.x * p4.x + p4.y * p4.y + p4.z * p4.z + p4.w * p4.w;
    wsum2(dt, pn);
    const float pdiv = fmaxf(sqrtf(pn), 1e-6f);
    sim[p] = clampf(dt / pdiv, -10.0f, 10.0f) * invt;
  }

  // softmax over P (redundant per lane)
  float m = sim[0];
#pragma unroll
  for (int p = 1; p < P; ++p) m = fmaxf(m, sim[p]);
  float ssum = 0.f;
#pragma unroll
  for (int p = 0; p < P; ++p) { sim[p] = expf(sim[p] - m); ssum += sim[p]; }
  const float sinv = 1.0f / ssum;
  float cand[4] = {0.f, 0.f, 0.f, 0.f};
#pragma unroll
  for (int p = 0; p < P; ++p) {
    const float a = clampf(sim[p] * sinv, 0.0f, 1.0f);
    cand[0] = fmaf(a, pv[p].x, cand[0]);
    cand[1] = fmaf(a, pv[p].y, cand[1]);
    cand[2] = fmaf(a, pv[p].z, cand[2]);
    cand[3] = fmaf(a, pv[p].w, cand[3]);
  }
#pragma unroll
  for (int i = 0; i < 4; ++i) cand[i] = clampf(cand[i], -5.0f, 5.0f);

  // gate
  const float rr[4] = {raw4.x, raw4.y, raw4.z, raw4.w};
  float gsum =
      clampf(rr[0], -50.f, 50.f) * wga.x + clampf(rr[1], -50.f, 50.f) * wga.y +
      clampf(rr[2], -50.f, 50.f) * wga.z + clampf(rr[3], -50.f, 50.f) * wga.w +
      clampf(cand[0], -50.f, 50.f) * wgb.x + clampf(cand[1], -50.f, 50.f) * wgb.y +
      clampf(cand[2], -50.f, 50.f) * wgb.z + clampf(cand[3], -50.f, 50.f) * wgb.w +
      clampf(t2.x, -50.f, 50.f) * wgt.x + clampf(t2.y, -50.f, 50.f) * wgt.y;
  const float z = clampf(wsum(gsum) + bgv, -10.0f, 10.0f);
  const float gate = 1.0f / (1.0f + expf(-z));

  // gated update + final LN + clip
  float upd[4];
  float s2 = 0.f;
#pragma unroll
  for (int i = 0; i < 4; ++i) {
    upd[i] = (1.0f - gate) * rr[i] + gate * cand[i];
    s2 += upd[i];
  }
  const float mu2 = wsum(s2) * (1.0f / 256.0f);
  float du[4];
  float v2 = 0.f;
#pragma unroll
  for (int i = 0; i < 4; ++i) { du[i] = upd[i] - mu2; v2 += du[i] * du[i]; }
  const float rstd2 = 1.0f / sqrtf(wsum(v2) * (1.0f / 256.0f) + 1e-6f);
  float4 y;
  y.x = clampf(du[0] * rstd2 * lnw4.x + lnb4.x, -10.0f, 10.0f);
  y.y = clampf(du[1] * rstd2 * lnw4.y + lnb4.y, -10.0f, 10.0f);
  y.z = clampf(du[2] * rstd2 * lnw4.z + lnb4.z, -10.0f, 10.0f);
  y.w = clampf(du[3] * rstd2 * lnw4.w + lnb4.w, -10.0f, 10.0f);
  *(float4*)(out + g * D + 4 * lane) = y;
}

// ---------------- fallback: fully fused (small ws), fp32 weights in-register ----------------
__global__ __launch_bounds__(256, 4) void fused_kernel(
    const float* __restrict__ raw, const float* __restrict__ edge,
    const float* __restrict__ tim, const float* __restrict__ proto,
    const float* __restrict__ Wq, const float* __restrict__ bq,
    const float* __restrict__ Wg, const float* __restrict__ bg,
    const float* __restrict__ temp, const float* __restrict__ lnw,
    const float* __restrict__ lnb, float* __restrict__ out) {
  __shared__ ushort qa[R][KP];
  __shared__ float qpre[R][DP];

  const int tid = threadIdx.x;
  const int r0 = blockIdx.x * R;

#pragma unroll
  for (int it = 0; it < (R * QIN / 4) / 256; ++it) {
    const int flat = it * 256 + tid;
    const int r = flat / (QIN / 4);
    const int p4 = (flat - r * (QIN / 4)) * 4;
    const size_t g = (size_t)(r0 + r);
    float4 v;
    if (p4 < D)          v = *(const float4*)(raw + g * D + p4);
    else if (p4 < D + E) v = *(const float4*)(edge + g * E + (p4 - D));
    else                 v = *(const float4*)(tim + g * T + (p4 - D - E));
    ushort4 h;
    h.x = f2bf(v.x); h.y = f2bf(v.y); h.z = f2bf(v.z); h.w = f2bf(v.w);
    *(ushort4*)&qa[r][p4] = h;
  }
  __syncthreads();

  const int w = tid >> 6;
  const int lane = tid & 63;
  const int lr = lane & 15;
  const int lh = lane >> 4;

  {
    f32x4 acc[4];
#pragma unroll
    for (int c = 0; c < 4; ++c) acc[c] = (f32x4){0.f, 0.f, 0.f, 0.f};
    for (int kb = 0; kb < QIN; kb += 32) {
      const bf16x8 af = *(const bf16x8*)&qa[lr][kb + lh * 8];
#pragma unroll
      for (int c = 0; c < 4; ++c) {
        const int n = w * 64 + c * 16 + lr;
        const float* src = Wq + (size_t)n * QIN + kb + lh * 8;
        const float4 a0 = *(const float4*)src;
        const float4 a1 = *(const float4*)(src + 4);
        bf16x8 bfv;
        bfv[0] = (short)f2bf(a0.x); bfv[1] = (short)f2bf(a0.y);
        bfv[2] = (short)f2bf(a0.z); bfv[3] = (short)f2bf(a0.w);
        bfv[4] = (short)f2bf(a1.x); bfv[5] = (short)f2bf(a1.y);
        bfv[6] = (short)f2bf(a1.z); bfv[7] = (short)f2bf(a1.w);
        acc[c] = __builtin_amdgcn_mfma_f32_16x16x32_bf16(af, bfv, acc[c], 0, 0, 0);
      }
    }
#pragma unroll
    for (int c = 0; c < 4; ++c) {
      const int n = w * 64 + c * 16 + lr;
      const float bqv = bq[n];
#pragma unroll
      for (int i = 0; i < 4; ++i) qpre[lh * 4 + i][n] = acc[c][i] + bqv;
    }
  }
  __syncthreads();

  const float4 lnw4 = *(const float4*)(lnw + 4 * lane);
  const float4 lnb4 = *(const float4*)(lnb + 4 * lane);
  const float lw[4] = {lnw4.x, lnw4.y, lnw4.z, lnw4.w};
  const float lb[4] = {lnb4.x, lnb4.y, lnb4.z, lnb4.w};
  const float4 wga = *(const float4*)(Wg + 4 * lane);
  const float4 wgb = *(const float4*)(Wg + D + 4 * lane);
  const float2 wgt = *(const float2*)(Wg + 2 * D + 2 * lane);
  const float bgv = bg[0];
  const float invt = 1.0f / (clampf(temp[0], 0.5f, 5.0f) + 0.01f);

  for (int r = w; r < R; r += 4) {
    const size_t g = (size_t)(r0 + r);
    const float4 x4 = *(const float4*)&qpre[r][4 * lane];
    float x[4] = {x4.x, x4.y, x4.z, x4.w};
    const float mu = wsum(x[0] + x[1] + x[2] + x[3]) * (1.0f / 256.0f);
    float dx[4];
    float v = 0.f;
#pragma unroll
    for (int i = 0; i < 4; ++i) { dx[i] = x[i] - mu; v += dx[i] * dx[i]; }
    const float rstd = 1.0f / sqrtf(wsum(v) * (1.0f / 256.0f) + 1e-6f);
    float q[4];
    float qs = 0.f;
#pragma unroll
    for (int i = 0; i < 4; ++i) {
      q[i] = tanhf(dx[i] * rstd * lw[i] + lb[i]);
      qs += q[i] * q[i];
    }
    const float qdiv = fmaxf(sqrtf(wsum(qs)), 1e-6f);

    const float* pb = proto + (g * P) * D + 4 * lane;
    float pv[P][4];
    float sim[P];
#pragma unroll
    for (int p = 0; p < P; ++p) {
      const float4 p4 = *(const float4*)(pb + (size_t)p * D);
      pv[p][0] = p4.x; pv[p][1] = p4.y; pv[p][2] = p4.z; pv[p][3] = p4.w;
      float dt = q[0] * p4.x + q[1] * p4.y + q[2] * p4.z + q[3] * p4.w;
      float pn = p4.x * p4.x + p4.y * p4.y + p4.z * p4.z + p4.w * p4.w;
      wsum2(dt, pn);
      const float pdiv = fmaxf(sqrtf(pn), 1e-6f);
      sim[p] = clampf(dt / (qdiv * pdiv), -10.0f, 10.0f) * invt;
    }
    float m = sim[0];
#pragma unroll
    for (int p = 1; p < P; ++p) m = fmaxf(m, sim[p]);
    float ssum = 0.f;
#pragma unroll
    for (int p = 0; p < P; ++p) { sim[p] = expf(sim[p] - m); ssum += sim[p]; }
    const float sinv = 1.0f / ssum;
    float cand[4] = {0.f, 0.f, 0.f, 0.f};
#pragma unroll
    for (int p = 0; p < P; ++p) {
      const float a = clampf(sim[p] * sinv, 0.0f, 1.0f);
#pragma unroll
      for (int i = 0; i < 4; ++i) cand[i] = fmaf(a, pv[p][i], cand[i]);
    }
#pragma unroll
    for (int i = 0; i < 4; ++i) cand[i] = clampf(cand[i], -5.0f, 5.0f);

    const float4 raw4 = *(const float4*)(raw + g * D + 4 * lane);
    const float rr[4] = {raw4.x, raw4.y, raw4.z, raw4.w};
    const float2 t2 = *(const float2*)(tim + g * T + 2 * lane);
    float gsum =
        clampf(rr[0], -50.f, 50.f) * wga.x + clampf(rr[1], -50.f, 50.f) * wga.y +
        clampf(rr[2], -50.f, 50.f) * wga.z + clampf(rr[3], -50.f, 50.f) * wga.w +
        clampf(cand[0], -50.f, 50.f) * wgb.x + clampf(cand[1], -50.f, 50.f) * wgb.y +
        clampf(cand[2], -50.f, 50.f) * wgb.z + clampf(cand[3], -50.f, 50.f) * wgb.w +
        clampf(t2.x, -50.f, 50.f) * wgt.x + clampf(t2.y, -50.f, 50.f) * wgt.y;
    const float z = clampf(wsum(gsum) + bgv, -10.0f, 10.0f);
    const float gate = 1.0f / (1.0f + expf(-z));

    float upd[4];
    float s2 = 0.f;
#pragma unroll
    for (int i = 0; i < 4; ++i) {
      upd[i] = (1.0f - gate) * rr[i] + gate * cand[i];
      s2 += upd[i];
    }
    const float mu2 = wsum(s2) * (1.0f / 256.0f);
    float du[4];
    float v2 = 0.f;
#pragma unroll
    for (int i = 0; i < 4; ++i) { du[i] = upd[i] - mu2; v2 += du[i] * du[i]; }
    const float rstd2 = 1.0f / sqrtf(wsum(v2) * (1.0f / 256.0f) + 1e-6f);
    float4 y;
    y.x = clampf(du[0] * rstd2 * lw[0] + lb[0], -10.0f, 10.0f);
    y.y = clampf(du[1] * rstd2 * lw[1] + lb[1], -10.0f, 10.0f);
    y.z = clampf(du[2] * rstd2 * lw[2] + lb[2], -10.0f, 10.0f);
    y.w = clampf(du[3] * rstd2 * lw[3] + lb[3], -10.0f, 10.0f);
    *(float4*)(out + g * D + 4 * lane) = y;
  }
}

extern "C" void kernel_launch(void* const* d_in, const int* in_sizes, int n_in,
                              void* d_out, int out_size, void* d_ws, size_t ws_size,
                              hipStream_t stream) {
  const float* raw   = (const float*)d_in[0];
  // d_in[1] = node_features: unused by the reference
  const float* edge  = (const float*)d_in[2];
  const float* tim   = (const float*)d_in[3];
  const float* proto = (const float*)d_in[4];
  const float* Wq    = (const float*)d_in[5];
  const float* bq    = (const float*)d_in[6];
  const float* Wg    = (const float*)d_in[7];
  const float* bg    = (const float*)d_in[8];
  const float* temp  = (const float*)d_in[9];
  const float* lnw   = (const float*)d_in[10];
  const float* lnb   = (const float*)d_in[11];
  float* out = (float*)d_out;

  const int B = in_sizes[0] / D;

  const size_t w2_bytes = (size_t)QIN * D * sizeof(ushort);            // 320 KB
  const size_t qn_bytes = (size_t)B * D * sizeof(ushort);              // 32 MB
  if (ws_size >= w2_bytes + qn_bytes) {
    ushort* W2 = (ushort*)d_ws;
    ushort* qn = (ushort*)((char*)d_ws + w2_bytes);
    prep_w2_kernel<<<(QIN * D) / 256, 256, 0, stream>>>(Wq, W2);
    qn_kernel<<<B / R, 256, 0, stream>>>(raw, edge, tim, W2, bq, lnw, lnb, qn);
    stream_kernel<<<B / 4, 256, 0, stream>>>(raw, tim, proto, qn, Wg, bg, temp,
                                             lnw, lnb, out);
  } else {
    fused_kernel<<<B / R, 256, 0, stream>>>(raw, edge, tim, proto, Wq, bq, Wg,
                                            bg, temp, lnw, lnb, out);
  }
}